// Round 8
// baseline (796952.148 us; speedup 1.0000x reference)
//
#include <hip/hip_runtime.h>
#include <hip/hip_bf16.h>

#define T_STEPS 128
#define NB 512
#define DHID 256
#define MEMS 256
#define ATT_IN 1536
#define GAMMA_IN 1792
#define HHID 512

// ---- workspace layout (floats), FULLY SEPARATED, total 6,422,528 fl = 24.5 MiB ----
#define OFF_H      0u          // [512,768]
#define OFF_C      393216u     // [512,768]
#define OFF_MEM    786432u     // [512,256]
#define ZERO_FLOATS 917504u
#define OFF_GATES  917504u     // [512,3072]
#define OFF_BOTH   2490368u    // [512,1792]
#define OFF_HIDA1  3407872u    // [512,512]
#define OFF_LOGITS 3670016u    // [512,1536]
#define OFF_HIDA2  4456448u    // [512,512]
#define OFF_CHAT   4718592u    // [512,256]
#define OFF_HIDG1  4849664u    // [512,512]
#define OFF_HIDG2  5111808u    // [512,512]
#define OFF_G1     5373952u    // [512,256]
#define OFF_G2     5505024u    // [512,256]
#define OFF_LAST   5636096u    // [512,1024]
#define OFF_HIDO   6160384u    // [512,512]
// end = 6422528

__device__ __forceinline__ float sigmoidf_(float x) { return 1.f / (1.f + expf(-x)); }

// Naive: C[n, col] = ACT( dot(A[n, :K], W[col, :K]) + b[col] ). One thread per output scalar.
template<int ACT>
__global__ __launch_bounds__(256) void naive_mm(
    const float* __restrict__ A, int lda,
    const float* __restrict__ W, int ldw, int K,
    const float* __restrict__ b,
    float* __restrict__ C, int ldc, int M, int N)
{
    int idx = blockIdx.x * 256 + threadIdx.x;
    if (idx >= M * N) return;
    int n = idx / N, col = idx - n * N;
    const float* a = A + (size_t)n * lda;
    const float* w = W + (size_t)col * ldw;
    float s = 0.f;
    for (int k = 0; k < K; ++k) s += a[k] * w[k];
    if (b) s += b[col];
    if (ACT == 1) s = fmaxf(s, 0.f);
    else if (ACT == 2) s = sigmoidf_(s);
    else if (ACT == 3) s = tanhf(s);
    C[(size_t)n * ldc + col] = s;
}

// gates[n, m*1024+j] = b_ih[j] + b_hh[j] + dot(x_m[n,:], W_ih[j,:]) + dot(h_m[n,:], W_hh[j,:])
__global__ __launch_bounds__(256) void gates_naive(
    const float* __restrict__ xl, const float* __restrict__ xa, const float* __restrict__ xv, int t,
    const float* __restrict__ Wih_l, const float* __restrict__ Whh_l, const float* __restrict__ bih_l, const float* __restrict__ bhh_l,
    const float* __restrict__ Wih_a, const float* __restrict__ Whh_a, const float* __restrict__ bih_a, const float* __restrict__ bhh_a,
    const float* __restrict__ Wih_v, const float* __restrict__ Whh_v, const float* __restrict__ bih_v, const float* __restrict__ bhh_v,
    const float* __restrict__ h, float* __restrict__ gates)
{
    int idx = blockIdx.x * 256 + threadIdx.x;      // 512*3072
    if (idx >= NB * 3072) return;
    int n = idx / 3072, col = idx - n * 3072;
    int m = col >> 10, j = col & 1023;
    const float* x; int D; const float* Wih; const float* Whh; const float* bi; const float* bh;
    if (m == 0)      { x = xl + (size_t)t * NB * 300; D = 300; Wih = Wih_l; Whh = Whh_l; bi = bih_l; bh = bhh_l; }
    else if (m == 1) { x = xa + (size_t)t * NB * 74;  D = 74;  Wih = Wih_a; Whh = Whh_a; bi = bih_a; bh = bhh_a; }
    else             { x = xv + (size_t)t * NB * 35;  D = 35;  Wih = Wih_v; Whh = Whh_v; bi = bih_v; bh = bhh_v; }
    float s = bi[j] + bh[j];
    const float* xr = x + (size_t)n * D;
    const float* wr = Wih + (size_t)j * D;
    for (int k = 0; k < D; ++k) s += xr[k] * wr[k];
    const float* hr = h + (size_t)n * 768 + m * DHID;
    const float* vr = Whh + (size_t)j * DHID;
    for (int k = 0; k < DHID; ++k) s += hr[k] * vr[k];
    gates[(size_t)n * 3072 + col] = s;
}

// LSTM elementwise; writes cStar = [c_old(768) | c_new(768)] into both[:, :1536]
__global__ __launch_bounds__(256) void cell_kernel(
    const float* __restrict__ gates, float* __restrict__ h,
    float* __restrict__ c, float* __restrict__ both)
{
    int idx = blockIdx.x * 256 + threadIdx.x;   // 512*768
    int n = idx / 768, jj = idx - n * 768;
    int m = jj >> 8, j = jj & 255;
    const float* g = gates + (size_t)n * 3072 + m * 1024;
    float gi = g[j], gf = g[256 + j], gz = g[512 + j], go = g[768 + j];
    float c_old = c[idx];
    both[(size_t)n * GAMMA_IN + jj] = c_old;
    float c_new = sigmoidf_(gf) * c_old + sigmoidf_(gi) * tanhf(gz);
    float h_new = sigmoidf_(go) * tanhf(c_new);
    c[idx] = c_new;
    h[idx] = h_new;
    both[(size_t)n * GAMMA_IN + 768 + jj] = c_new;
}

// one wave per row: both[n, :1536] *= softmax(logits[n, :]); both[n, 1536:] = mem[n, :]
__global__ __launch_bounds__(64) void attend_naive(
    const float* __restrict__ logits, const float* __restrict__ mem, float* __restrict__ both)
{
    int n = blockIdx.x;
    int lane = threadIdx.x;     // 0..63
    const float* lr = logits + (size_t)n * ATT_IN;
    float v[24];
    float mx = -3.4e38f;
    #pragma unroll
    for (int q = 0; q < 24; ++q) { v[q] = lr[q * 64 + lane]; mx = fmaxf(mx, v[q]); }
    #pragma unroll
    for (int o = 32; o; o >>= 1) mx = fmaxf(mx, __shfl_xor(mx, o));
    float s = 0.f;
    #pragma unroll
    for (int q = 0; q < 24; ++q) { v[q] = expf(v[q] - mx); s += v[q]; }
    #pragma unroll
    for (int o = 32; o; o >>= 1) s += __shfl_xor(s, o);
    float inv = 1.f / s;
    float* br = both + (size_t)n * GAMMA_IN;
    #pragma unroll
    for (int q = 0; q < 24; ++q) br[q * 64 + lane] *= v[q] * inv;
    const float* mr = mem + (size_t)n * MEMS;
    #pragma unroll
    for (int q = 0; q < 4; ++q) br[ATT_IN + q * 64 + lane] = mr[q * 64 + lane];
}

__global__ __launch_bounds__(256) void mem_update_kernel(
    const float* __restrict__ g1, const float* __restrict__ g2,
    const float* __restrict__ cHat, float* __restrict__ mem)
{
    int idx = blockIdx.x * 256 + threadIdx.x;   // 512*256
    mem[idx] = g1[idx] * mem[idx] + g2[idx] * cHat[idx];
}

__global__ __launch_bounds__(256) void concat_last_kernel(
    const float* __restrict__ h, const float* __restrict__ mem, float* __restrict__ last)
{
    int idx = blockIdx.x * 256 + threadIdx.x;   // 512*1024
    int n = idx >> 10, j = idx & 1023;
    last[idx] = (j < 768) ? h[(size_t)n * 768 + j] : mem[(size_t)n * 256 + (j - 768)];
}

// one wave per row: out[n] = dot(hidO[n,:512], w2[:512]) + b2[0]   (fp32 output!)
__global__ __launch_bounds__(64) void final_out_naive(
    const float* __restrict__ hidO, const float* __restrict__ w2,
    const float* __restrict__ b2, float* __restrict__ out)
{
    int n = blockIdx.x;
    int lane = threadIdx.x;
    const float* hr = hidO + (size_t)n * 512;
    float s = 0.f;
    #pragma unroll
    for (int q = 0; q < 8; ++q) s += hr[q * 64 + lane] * w2[q * 64 + lane];
    #pragma unroll
    for (int o = 32; o; o >>= 1) s += __shfl_xor(s, o);
    if (lane == 0) out[n] = s + b2[0];
}

extern "C" void kernel_launch(void* const* d_in, const int* in_sizes, int n_in,
                              void* d_out, int out_size, void* d_ws, size_t ws_size,
                              hipStream_t stream)
{
    const float* x_l = (const float*)d_in[0];
    const float* x_a = (const float*)d_in[1];
    const float* x_v = (const float*)d_in[2];
    const float* W_ih_l = (const float*)d_in[3];
    const float* W_hh_l = (const float*)d_in[4];
    const float* b_ih_l = (const float*)d_in[5];
    const float* b_hh_l = (const float*)d_in[6];
    const float* W_ih_a = (const float*)d_in[7];
    const float* W_hh_a = (const float*)d_in[8];
    const float* b_ih_a = (const float*)d_in[9];
    const float* b_hh_a = (const float*)d_in[10];
    const float* W_ih_v = (const float*)d_in[11];
    const float* W_hh_v = (const float*)d_in[12];
    const float* b_ih_v = (const float*)d_in[13];
    const float* b_hh_v = (const float*)d_in[14];
    const float* att1_w1 = (const float*)d_in[15];
    const float* att1_b1 = (const float*)d_in[16];
    const float* att1_w2 = (const float*)d_in[17];
    const float* att1_b2 = (const float*)d_in[18];
    const float* att2_w1 = (const float*)d_in[19];
    const float* att2_b1 = (const float*)d_in[20];
    const float* att2_w2 = (const float*)d_in[21];
    const float* att2_b2 = (const float*)d_in[22];
    const float* g1_w1 = (const float*)d_in[23];
    const float* g1_b1 = (const float*)d_in[24];
    const float* g1_w2 = (const float*)d_in[25];
    const float* g1_b2 = (const float*)d_in[26];
    const float* g2_w1 = (const float*)d_in[27];
    const float* g2_b1 = (const float*)d_in[28];
    const float* g2_w2 = (const float*)d_in[29];
    const float* g2_b2 = (const float*)d_in[30];
    const float* out_w1 = (const float*)d_in[31];
    const float* out_b1 = (const float*)d_in[32];
    const float* out_w2 = (const float*)d_in[33];
    const float* out_b2 = (const float*)d_in[34];

    float* ws = (float*)d_ws;
    float* h      = ws + OFF_H;
    float* c      = ws + OFF_C;
    float* memb   = ws + OFF_MEM;
    float* gates  = ws + OFF_GATES;
    float* both   = ws + OFF_BOTH;
    float* hidA1  = ws + OFF_HIDA1;
    float* logits = ws + OFF_LOGITS;
    float* hidA2  = ws + OFF_HIDA2;
    float* cHat   = ws + OFF_CHAT;
    float* hidG1  = ws + OFF_HIDG1;
    float* hidG2  = ws + OFF_HIDG2;
    float* g1     = ws + OFF_G1;
    float* g2     = ws + OFF_G2;
    float* last   = ws + OFF_LAST;
    float* hidO   = ws + OFF_HIDO;

    hipMemsetAsync(h, 0, ZERO_FLOATS * sizeof(float), stream);

    dim3 blk(256);
    for (int t = 0; t < T_STEPS; ++t) {
        gates_naive<<<6144, blk, 0, stream>>>(x_l, x_a, x_v, t,
            W_ih_l, W_hh_l, b_ih_l, b_hh_l,
            W_ih_a, W_hh_a, b_ih_a, b_hh_a,
            W_ih_v, W_hh_v, b_ih_v, b_hh_v,
            h, gates);
        cell_kernel<<<1536, blk, 0, stream>>>(gates, h, c, both);
        // att1: relu(cStar @ w1^T + b1) -> hidA1 ; hidA1 @ w2^T + b2 -> logits
        naive_mm<1><<<1024, blk, 0, stream>>>(both, GAMMA_IN, att1_w1, ATT_IN, ATT_IN, att1_b1, hidA1, HHID, NB, HHID);
        naive_mm<0><<<3072, blk, 0, stream>>>(hidA1, HHID, att1_w2, HHID, HHID, att1_b2, logits, ATT_IN, NB, ATT_IN);
        attend_naive<<<512, 64, 0, stream>>>(logits, memb, both);
        // att2: relu -> hidA2 ; tanh -> cHat
        naive_mm<1><<<1024, blk, 0, stream>>>(both, GAMMA_IN, att2_w1, ATT_IN, ATT_IN, att2_b1, hidA2, HHID, NB, HHID);
        naive_mm<3><<<512, blk, 0, stream>>>(hidA2, HHID, att2_w2, HHID, HHID, att2_b2, cHat, MEMS, NB, MEMS);
        // gamma1 / gamma2
        naive_mm<1><<<1024, blk, 0, stream>>>(both, GAMMA_IN, g1_w1, GAMMA_IN, GAMMA_IN, g1_b1, hidG1, HHID, NB, HHID);
        naive_mm<1><<<1024, blk, 0, stream>>>(both, GAMMA_IN, g2_w1, GAMMA_IN, GAMMA_IN, g2_b1, hidG2, HHID, NB, HHID);
        naive_mm<2><<<512, blk, 0, stream>>>(hidG1, HHID, g1_w2, HHID, HHID, g1_b2, g1, MEMS, NB, MEMS);
        naive_mm<2><<<512, blk, 0, stream>>>(hidG2, HHID, g2_w2, HHID, HHID, g2_b2, g2, MEMS, NB, MEMS);
        mem_update_kernel<<<512, blk, 0, stream>>>(g1, g2, cHat, memb);
    }

    concat_last_kernel<<<2048, blk, 0, stream>>>(h, memb, last);
    naive_mm<1><<<1024, blk, 0, stream>>>(last, 1024, out_w1, 1024, 1024, out_b1, hidO, HHID, NB, HHID);
    final_out_naive<<<512, 64, 0, stream>>>(hidO, out_w2, out_b2, (float*)d_out);
}

// Round 9
// 71844.440 us; speedup vs baseline: 11.0927x; 11.0927x over previous
//
#include <hip/hip_runtime.h>
#include <hip/hip_bf16.h>

#define T_STEPS 128
#define NB 512
#define DHID 256
#define MEMS 256
#define ATT_IN 1536
#define GAMMA_IN 1792
#define HHID 512

#define TILE_M 64
#define TILE_N 64
#define TILE_K 16

// ---- workspace layout (floats), total 6,422,528 fl = 24.5 MiB (size proven in R8) ----
#define OFF_H      0u          // [512,768]
#define OFF_C      393216u     // [512,768]
#define OFF_MEM    786432u     // [512,256]
#define ZERO_FLOATS 917504u
#define OFF_GATES  917504u     // [512,3072]
#define OFF_BOTH   2490368u    // [512,1792]  cStar|mem -> attended|mem
#define OFF_HIDA1  3407872u    // [512,512]
#define OFF_LOGITS 3670016u    // [512,1536]
#define OFF_HIDF   4456448u    // [512,1536]  att2hid|g1hid|g2hid
#define OFF_GGC    5242880u    // [512,768]   cHat|g1|g2
#define OFF_LAST   5636096u    // [512,1024]
#define OFF_HIDO   6160384u    // [512,512]
// end = 6422528

__device__ __forceinline__ float sigmoidf_(float x) { return 1.f / (1.f + expf(-x)); }

// C[M,N] (stride ldc) = act( A@B^T (+ A2@B2^T) + bias (+ bias2) )
// A [M,K] rm stride lda; B [N,K] rm stride ldb. blockDim=256. ACT==-1 -> runtime ract.
template<int ACT>
__device__ __forceinline__ void gemm_body(
    const float* __restrict__ A, int lda,
    const float* __restrict__ B, int ldb, int K,
    const float* __restrict__ A2, int lda2,
    const float* __restrict__ B2, int ldb2, int K2,
    const float* __restrict__ bias, const float* __restrict__ bias2,
    float* __restrict__ C, int ldc, int M, int N, int ract = 0)
{
    __shared__ float As[TILE_K][TILE_M];
    __shared__ float Bs[TILE_K][TILE_N];

    const int tid = threadIdx.x;        // 0..255
    const int tx = tid & 15;            // col group
    const int ty = tid >> 4;            // row group
    const int row0 = blockIdx.y * TILE_M;
    const int col0 = blockIdx.x * TILE_N;

    const int lrow = tid >> 2;          // 0..63
    const int lk4  = (tid & 3) * 4;     // 0,4,8,12

    float acc[4][4] = {};

    for (int phase = 0; phase < 2; ++phase) {
        const float* Ap = (phase == 0) ? A : A2;
        if (Ap == nullptr) continue;
        const float* Bp = (phase == 0) ? B : B2;
        const int Kp   = (phase == 0) ? K : K2;
        const int ldap = (phase == 0) ? lda : lda2;
        const int ldbp = (phase == 0) ? ldb : ldb2;

        for (int k0 = 0; k0 < Kp; k0 += TILE_K) {
            #pragma unroll
            for (int q = 0; q < 4; ++q) {
                int k = k0 + lk4 + q;
                float va = 0.f, vb = 0.f;
                if (k < Kp) {
                    int ar = row0 + lrow;
                    if (ar < M) va = Ap[(size_t)ar * ldap + k];
                    int br = col0 + lrow;
                    if (br < N) vb = Bp[(size_t)br * ldbp + k];
                }
                As[lk4 + q][lrow] = va;
                Bs[lk4 + q][lrow] = vb;
            }
            __syncthreads();
            #pragma unroll
            for (int k = 0; k < TILE_K; ++k) {
                float4 a4 = *reinterpret_cast<const float4*>(&As[k][ty * 4]);
                float4 b4 = *reinterpret_cast<const float4*>(&Bs[k][tx * 4]);
                acc[0][0] += a4.x * b4.x; acc[0][1] += a4.x * b4.y; acc[0][2] += a4.x * b4.z; acc[0][3] += a4.x * b4.w;
                acc[1][0] += a4.y * b4.x; acc[1][1] += a4.y * b4.y; acc[1][2] += a4.y * b4.z; acc[1][3] += a4.y * b4.w;
                acc[2][0] += a4.z * b4.x; acc[2][1] += a4.z * b4.y; acc[2][2] += a4.z * b4.z; acc[2][3] += a4.z * b4.w;
                acc[3][0] += a4.w * b4.x; acc[3][1] += a4.w * b4.y; acc[3][2] += a4.w * b4.z; acc[3][3] += a4.w * b4.w;
            }
            __syncthreads();
        }
    }

    const int act = (ACT == -1) ? ract : ACT;
    #pragma unroll
    for (int i = 0; i < 4; ++i) {
        int r = row0 + ty * 4 + i;
        if (r >= M) continue;
        #pragma unroll
        for (int j = 0; j < 4; ++j) {
            int cc = col0 + tx * 4 + j;
            if (cc >= N) continue;
            float v = acc[i][j];
            if (bias)  v += bias[cc];
            if (bias2) v += bias2[cc];
            if (act == 1) v = fmaxf(v, 0.f);
            else if (act == 2) v = sigmoidf_(v);
            else if (act == 3) v = tanhf(v);
            C[(size_t)r * ldc + cc] = v;
        }
    }
}

template<int ACT>
__global__ __launch_bounds__(256) void gemm_kernel(
    const float* __restrict__ A, int lda,
    const float* __restrict__ B, int ldb, int K,
    const float* __restrict__ bias,
    float* __restrict__ C, int ldc, int M, int N)
{
    gemm_body<ACT>(A, lda, B, ldb, K, nullptr, 0, nullptr, 0, 0, bias, nullptr, C, ldc, M, N);
}

// gates[:, m*1024:(m+1)*1024] = x_m@W_ih^T + h_m@W_hh^T + b_ih + b_hh  (dual-phase, one dispatch)
__global__ __launch_bounds__(256) void gates_kernel(
    const float* __restrict__ xl, const float* __restrict__ xa, const float* __restrict__ xv, int t,
    const float* __restrict__ Wih_l, const float* __restrict__ Whh_l, const float* __restrict__ bih_l, const float* __restrict__ bhh_l,
    const float* __restrict__ Wih_a, const float* __restrict__ Whh_a, const float* __restrict__ bih_a, const float* __restrict__ bhh_a,
    const float* __restrict__ Wih_v, const float* __restrict__ Whh_v, const float* __restrict__ bih_v, const float* __restrict__ bhh_v,
    const float* __restrict__ h, float* __restrict__ gates)
{
    int m = blockIdx.z;
    const float* x; int D; const float* Wih; const float* Whh; const float* bi; const float* bh;
    if (m == 0)      { x = xl + (size_t)t * NB * 300; D = 300; Wih = Wih_l; Whh = Whh_l; bi = bih_l; bh = bhh_l; }
    else if (m == 1) { x = xa + (size_t)t * NB * 74;  D = 74;  Wih = Wih_a; Whh = Whh_a; bi = bih_a; bh = bhh_a; }
    else             { x = xv + (size_t)t * NB * 35;  D = 35;  Wih = Wih_v; Whh = Whh_v; bi = bih_v; bh = bhh_v; }
    gemm_body<0>(x, D, Wih, D, D,
                 h + m * DHID, 768, Whh, DHID, DHID,
                 bi, bh, gates + m * 1024, 3072, NB, 1024);
}

// fused att2/g1/g2 layer-1: z=0: attended@att2_w1^T (K=1536); z=1/2: both@g_w1^T (K=1792)
__global__ __launch_bounds__(256) void fused_l1_kernel(
    const float* __restrict__ both,
    const float* __restrict__ att2_w1, const float* __restrict__ att2_b1,
    const float* __restrict__ g1_w1, const float* __restrict__ g1_b1,
    const float* __restrict__ g2_w1, const float* __restrict__ g2_b1,
    float* __restrict__ hidF)
{
    int z = blockIdx.z;
    const float* W; const float* b; int K;
    if (z == 0)      { W = att2_w1; b = att2_b1; K = ATT_IN; }
    else if (z == 1) { W = g1_w1;   b = g1_b1;   K = GAMMA_IN; }
    else             { W = g2_w1;   b = g2_b1;   K = GAMMA_IN; }
    gemm_body<1>(both, GAMMA_IN, W, K, K, nullptr, 0, nullptr, 0, 0,
                 b, nullptr, hidF + z * HHID, 1536, NB, HHID);
}

// fused layer-2: z=0: tanh(att2hid@att2_w2^T) -> ggc[:, :256]; z=1/2: sigmoid -> ggc[:, 256/512:]
__global__ __launch_bounds__(256) void fused_l2_kernel(
    const float* __restrict__ hidF,
    const float* __restrict__ att2_w2, const float* __restrict__ att2_b2,
    const float* __restrict__ g1_w2, const float* __restrict__ g1_b2,
    const float* __restrict__ g2_w2, const float* __restrict__ g2_b2,
    float* __restrict__ ggc)
{
    int z = blockIdx.z;
    const float* W; const float* b; int act;
    if (z == 0)      { W = att2_w2; b = att2_b2; act = 3; }
    else if (z == 1) { W = g1_w2;   b = g1_b2;   act = 2; }
    else             { W = g2_w2;   b = g2_b2;   act = 2; }
    gemm_body<-1>(hidF + z * HHID, 1536, W, HHID, HHID, nullptr, 0, nullptr, 0, 0,
                  b, nullptr, ggc + z * MEMS, 768, NB, MEMS, act);
}

// LSTM elementwise; writes cStar = [c_old(768) | c_new(768)] into both[:, :1536]
__global__ __launch_bounds__(256) void cell_kernel(
    const float* __restrict__ gates, float* __restrict__ h,
    float* __restrict__ c, float* __restrict__ both)
{
    int idx = blockIdx.x * 256 + threadIdx.x;   // 512*768
    int n = idx / 768, jj = idx - n * 768;
    int m = jj >> 8, j = jj & 255;
    const float* g = gates + (size_t)n * 3072 + m * 1024;
    float gi = g[j], gf = g[256 + j], gz = g[512 + j], go = g[768 + j];
    float c_old = c[idx];
    both[(size_t)n * GAMMA_IN + jj] = c_old;
    float c_new = sigmoidf_(gf) * c_old + sigmoidf_(gi) * tanhf(gz);
    float h_new = sigmoidf_(go) * tanhf(c_new);
    c[idx] = c_new;
    h[idx] = h_new;
    both[(size_t)n * GAMMA_IN + 768 + jj] = c_new;
}

// one wave per row: both[n, :1536] *= softmax(logits[n, :]); both[n, 1536:] = mem[n, :]
__global__ __launch_bounds__(64) void attend_naive(
    const float* __restrict__ logits, const float* __restrict__ mem, float* __restrict__ both)
{
    int n = blockIdx.x;
    int lane = threadIdx.x;     // 0..63
    const float* lr = logits + (size_t)n * ATT_IN;
    float v[24];
    float mx = -3.4e38f;
    #pragma unroll
    for (int q = 0; q < 24; ++q) { v[q] = lr[q * 64 + lane]; mx = fmaxf(mx, v[q]); }
    #pragma unroll
    for (int o = 32; o; o >>= 1) mx = fmaxf(mx, __shfl_xor(mx, o));
    float s = 0.f;
    #pragma unroll
    for (int q = 0; q < 24; ++q) { v[q] = expf(v[q] - mx); s += v[q]; }
    #pragma unroll
    for (int o = 32; o; o >>= 1) s += __shfl_xor(s, o);
    float inv = 1.f / s;
    float* br = both + (size_t)n * GAMMA_IN;
    #pragma unroll
    for (int q = 0; q < 24; ++q) br[q * 64 + lane] *= v[q] * inv;
    const float* mr = mem + (size_t)n * MEMS;
    #pragma unroll
    for (int q = 0; q < 4; ++q) br[ATT_IN + q * 64 + lane] = mr[q * 64 + lane];
}

// mem = g1*mem + g2*cHat  with ggc = [cHat(256) | g1(256) | g2(256)]
__global__ __launch_bounds__(256) void mem_update_kernel(
    const float* __restrict__ ggc, float* __restrict__ mem)
{
    int idx = blockIdx.x * 256 + threadIdx.x;   // 512*256
    int n = idx >> 8, j = idx & 255;
    const float* gr = ggc + (size_t)n * 768;
    mem[idx] = gr[256 + j] * mem[idx] + gr[512 + j] * gr[j];
}

__global__ __launch_bounds__(256) void concat_last_kernel(
    const float* __restrict__ h, const float* __restrict__ mem, float* __restrict__ last)
{
    int idx = blockIdx.x * 256 + threadIdx.x;   // 512*1024
    int n = idx >> 10, j = idx & 1023;
    last[idx] = (j < 768) ? h[(size_t)n * 768 + j] : mem[(size_t)n * 256 + (j - 768)];
}

// one wave per row: out[n] = dot(hidO[n,:512], w2[:512]) + b2[0]   (fp32 output)
__global__ __launch_bounds__(64) void final_out_naive(
    const float* __restrict__ hidO, const float* __restrict__ w2,
    const float* __restrict__ b2, float* __restrict__ out)
{
    int n = blockIdx.x;
    int lane = threadIdx.x;
    const float* hr = hidO + (size_t)n * 512;
    float s = 0.f;
    #pragma unroll
    for (int q = 0; q < 8; ++q) s += hr[q * 64 + lane] * w2[q * 64 + lane];
    #pragma unroll
    for (int o = 32; o; o >>= 1) s += __shfl_xor(s, o);
    if (lane == 0) out[n] = s + b2[0];
}

extern "C" void kernel_launch(void* const* d_in, const int* in_sizes, int n_in,
                              void* d_out, int out_size, void* d_ws, size_t ws_size,
                              hipStream_t stream)
{
    const float* x_l = (const float*)d_in[0];
    const float* x_a = (const float*)d_in[1];
    const float* x_v = (const float*)d_in[2];
    const float* W_ih_l = (const float*)d_in[3];
    const float* W_hh_l = (const float*)d_in[4];
    const float* b_ih_l = (const float*)d_in[5];
    const float* b_hh_l = (const float*)d_in[6];
    const float* W_ih_a = (const float*)d_in[7];
    const float* W_hh_a = (const float*)d_in[8];
    const float* b_ih_a = (const float*)d_in[9];
    const float* b_hh_a = (const float*)d_in[10];
    const float* W_ih_v = (const float*)d_in[11];
    const float* W_hh_v = (const float*)d_in[12];
    const float* b_ih_v = (const float*)d_in[13];
    const float* b_hh_v = (const float*)d_in[14];
    const float* att1_w1 = (const float*)d_in[15];
    const float* att1_b1 = (const float*)d_in[16];
    const float* att1_w2 = (const float*)d_in[17];
    const float* att1_b2 = (const float*)d_in[18];
    const float* att2_w1 = (const float*)d_in[19];
    const float* att2_b1 = (const float*)d_in[20];
    const float* att2_w2 = (const float*)d_in[21];
    const float* att2_b2 = (const float*)d_in[22];
    const float* g1_w1 = (const float*)d_in[23];
    const float* g1_b1 = (const float*)d_in[24];
    const float* g1_w2 = (const float*)d_in[25];
    const float* g1_b2 = (const float*)d_in[26];
    const float* g2_w1 = (const float*)d_in[27];
    const float* g2_b1 = (const float*)d_in[28];
    const float* g2_w2 = (const float*)d_in[29];
    const float* g2_b2 = (const float*)d_in[30];
    const float* out_w1 = (const float*)d_in[31];
    const float* out_b1 = (const float*)d_in[32];
    const float* out_w2 = (const float*)d_in[33];
    const float* out_b2 = (const float*)d_in[34];

    float* ws = (float*)d_ws;
    float* h      = ws + OFF_H;
    float* c      = ws + OFF_C;
    float* memb   = ws + OFF_MEM;
    float* gates  = ws + OFF_GATES;
    float* both   = ws + OFF_BOTH;
    float* hidA1  = ws + OFF_HIDA1;
    float* logits = ws + OFF_LOGITS;
    float* hidF   = ws + OFF_HIDF;
    float* ggc    = ws + OFF_GGC;
    float* last   = ws + OFF_LAST;
    float* hidO   = ws + OFF_HIDO;

    hipMemsetAsync(h, 0, ZERO_FLOATS * sizeof(float), stream);

    dim3 blk(256);
    for (int t = 0; t < T_STEPS; ++t) {
        gates_kernel<<<dim3(16, 8, 3), blk, 0, stream>>>(x_l, x_a, x_v, t,
            W_ih_l, W_hh_l, b_ih_l, b_hh_l,
            W_ih_a, W_hh_a, b_ih_a, b_hh_a,
            W_ih_v, W_hh_v, b_ih_v, b_hh_v,
            h, gates);
        cell_kernel<<<1536, blk, 0, stream>>>(gates, h, c, both);
        // att1: relu(cStar @ w1^T + b1) -> hidA1 ; hidA1 @ w2^T + b2 -> logits
        gemm_kernel<1><<<dim3(8, 8), blk, 0, stream>>>(both, GAMMA_IN, att1_w1, ATT_IN, ATT_IN, att1_b1, hidA1, HHID, NB, HHID);
        gemm_kernel<0><<<dim3(24, 8), blk, 0, stream>>>(hidA1, HHID, att1_w2, HHID, HHID, att1_b2, logits, ATT_IN, NB, ATT_IN);
        attend_naive<<<512, 64, 0, stream>>>(logits, memb, both);
        // att2/g1/g2 layer-1 fused (one dispatch, z in {0,1,2})
        fused_l1_kernel<<<dim3(8, 8, 3), blk, 0, stream>>>(both,
            att2_w1, att2_b1, g1_w1, g1_b1, g2_w1, g2_b1, hidF);
        // att2/g1/g2 layer-2 fused -> ggc = cHat|g1|g2
        fused_l2_kernel<<<dim3(4, 8, 3), blk, 0, stream>>>(hidF,
            att2_w2, att2_b2, g1_w2, g1_b2, g2_w2, g2_b2, ggc);
        mem_update_kernel<<<512, blk, 0, stream>>>(ggc, memb);
    }

    concat_last_kernel<<<2048, blk, 0, stream>>>(h, memb, last);
    gemm_kernel<1><<<dim3(8, 8), blk, 0, stream>>>(last, 1024, out_w1, 1024, 1024, out_b1, hidO, HHID, NB, HHID);
    final_out_naive<<<512, 64, 0, stream>>>(hidO, out_w2, out_b2, (float*)d_out);
}